// Round 9
// baseline (688.657 us; speedup 1.0000x reference)
//
#include <hip/hip_runtime.h>
#include <hip/hip_bf16.h>

#define C_CH 512
#define HW 16384
#define NB 8
#define BK 32                    // f32 k-elements per K-step (= MFMA K)
#define KSPLIT 16
#define KCHUNK (HW / KSPLIT)     // 1024
#define KSTEPS (KCHUNK / BK)     // 32
#define NGRAM 16
#define CC (C_CH * C_CH)
#define LOSS_BLOCKS 1024
#define SLOTS (C_CH * (BK / 4))  // 4096 f32x4 slots = 64 KiB per buffer

typedef float f32x4 __attribute__((ext_vector_type(4)));
typedef __bf16 bf16x8 __attribute__((ext_vector_type(8)));

#define GLOAD_LDS16(gsrc, ldst)                                                 \
    __builtin_amdgcn_global_load_lds(                                           \
        (const __attribute__((address_space(1))) void*)(gsrc),                  \
        (__attribute__((address_space(3))) void*)(ldst), 16, 0, 0)

// triangular frag index for m<=n in an 8x8 upper triangle (36 entries)
#define TRI(m, n) (8 * (m) - ((m) * ((m)-1)) / 2 + (n) - (m))

// One block per (gram g, k-slice ks): full 512x512 triangular gram.
// Panel staged once per K-step -> every input byte issued EXACTLY once (512 MB
// total, 4x less than tile-per-block variants). 8 waves: 6 off-diag 128^2
// tiles + 2 waves with 2 diag tiles each (diag reuses A-frags as B-operands).
// LDS: f32 panel via global_load_lds, linear dest + involution-swizzled global
// source (chunk ^ row&7); fragment reads apply the same XOR -> conflict-free.
__global__ __launch_bounds__(512, 1) void gram_kernel(const float* __restrict__ det,
                                                      const float* __restrict__ sr,
                                                      float* __restrict__ gram) {
    const int g = blockIdx.x >> 4;       // 0..15
    const int ks = blockIdx.x & 15;
    const int tensor = g >> 3, b = g & 7;
    const float* F = (tensor ? sr : det) + (size_t)b * C_CH * HW + ks * KCHUNK;

    __shared__ f32x4 lds[2][SLOTS];      // 128 KiB double buffer

    const int tid = threadIdx.x;
    const int lane = tid & 63;
    const int wid = tid >> 6;
    const int kg = lane >> 4;            // 0..3: selects k-chunk pair 2kg, 2kg+1
    const int l15 = lane & 15;

    // wave -> off-diag tile map: wid0..5 -> (0,1),(0,2),(0,3),(1,2),(1,3),(2,3)
    const int ti = (wid < 3) ? 0 : (wid < 5) ? 1 : 2;
    const int tj = (wid < 3) ? wid + 1 : (wid < 5) ? wid - 1 : 3;  // FIX: wid-1 (was wid-2)
    const int ta = (wid == 6) ? 0 : 1;   // diag-wave tile pair
    const int tb = (wid == 6) ? 3 : 2;

    // stage: slot f = q*512+tid (LDS linear: wave-uniform base + lane*16);
    // logical (row R=f>>3, slot s=f&7) holds global chunk s ^ (R&7)
    auto STAGE = [&](int buf, int kt) {
        const float* src = F + kt * BK;
        #pragma unroll
        for (int q = 0; q < 8; ++q) {
            int f = q * 512 + tid;
            int R = f >> 3, s = f & 7;
            int c = s ^ (R & 7);
            GLOAD_LDS16(src + (size_t)R * HW + c * 4, &lds[buf][f]);
        }
    };

    // read one 16x16x32 fragment (lane row = base+l15): 8 f32 of
    // k = kg*8 .. kg*8+7 from chunks 2kg, 2kg+1 (XOR-inverted), cvt to bf16
    auto rdfrag = [&](const f32x4* P, int R) {
        f32x4 lo = P[R * 8 + ((2 * kg) ^ (R & 7))];
        f32x4 hi = P[R * 8 + ((2 * kg + 1) ^ (R & 7))];
        bf16x8 h;
        #pragma unroll
        for (int i = 0; i < 4; ++i) { h[i] = (__bf16)lo[i]; h[4 + i] = (__bf16)hi[i]; }
        return h;
    };

    // acc union: off-diag waves use [m*8+n] (64 used); diag waves use
    // [TRI(m,n)] tileA + [36+TRI(m,n)] tileB (72 used). All static indices.
    f32x4 acc[72];
    #pragma unroll
    for (int i = 0; i < 72; ++i) acc[i] = f32x4{0.f, 0.f, 0.f, 0.f};

    STAGE(0, 0);
    __syncthreads();
    int cur = 0;

    #pragma unroll 1
    for (int kt = 0; kt < KSTEPS; ++kt) {
        if (kt + 1 < KSTEPS) STAGE(cur ^ 1, kt + 1);   // fire-and-forget DMA
        const f32x4* P = &lds[cur][0];

        if (wid < 6) {
            // off-diagonal 128x128 tile (ti,tj)
            bf16x8 af[8];
            #pragma unroll
            for (int m = 0; m < 8; ++m) af[m] = rdfrag(P, ti * 128 + m * 16 + l15);
            #pragma unroll
            for (int n = 0; n < 8; ++n) {
                bf16x8 bfr = rdfrag(P, tj * 128 + n * 16 + l15);
                #pragma unroll
                for (int m = 0; m < 8; ++m)
                    acc[m * 8 + n] = __builtin_amdgcn_mfma_f32_16x16x32_bf16(
                        af[m], bfr, acc[m * 8 + n], 0, 0, 0);
            }
        } else {
            // two diagonal tiles; B-frag == A-frag for Gram (layouts coincide)
            bf16x8 af[8];
            #pragma unroll
            for (int m = 0; m < 8; ++m) af[m] = rdfrag(P, ta * 128 + m * 16 + l15);
            #pragma unroll
            for (int m = 0; m < 8; ++m)
                #pragma unroll
                for (int n = m; n < 8; ++n)
                    acc[TRI(m, n)] = __builtin_amdgcn_mfma_f32_16x16x32_bf16(
                        af[m], af[n], acc[TRI(m, n)], 0, 0, 0);
            #pragma unroll
            for (int m = 0; m < 8; ++m) af[m] = rdfrag(P, tb * 128 + m * 16 + l15);
            #pragma unroll
            for (int m = 0; m < 8; ++m)
                #pragma unroll
                for (int n = m; n < 8; ++n)
                    acc[36 + TRI(m, n)] = __builtin_amdgcn_mfma_f32_16x16x32_bf16(
                        af[m], af[n], acc[36 + TRI(m, n)], 0, 0, 0);
        }
        __syncthreads();   // also drains the STAGE vmcnt (covered by compute+HBM wait)
        cur ^= 1;
    }

    // epilogue: C/D layout col=lane&15, row=(lane>>4)*4+j
    float* gout = gram + (size_t)g * CC;
    const int rq = kg << 2;
    if (wid < 6) {
        #pragma unroll
        for (int m = 0; m < 8; ++m)
            #pragma unroll
            for (int n = 0; n < 8; ++n) {
                int row = ti * 128 + m * 16 + rq;
                int col = tj * 128 + n * 16 + l15;
                #pragma unroll
                for (int j = 0; j < 4; ++j)
                    atomicAdd(&gout[(size_t)(row + j) * C_CH + col], acc[m * 8 + n][j]);
            }
    } else {
        #pragma unroll
        for (int m = 0; m < 8; ++m)
            #pragma unroll
            for (int n = m; n < 8; ++n) {
                int row = ta * 128 + m * 16 + rq;
                int col = ta * 128 + n * 16 + l15;
                #pragma unroll
                for (int j = 0; j < 4; ++j)
                    atomicAdd(&gout[(size_t)(row + j) * C_CH + col], acc[TRI(m, n)][j]);
            }
        #pragma unroll
        for (int m = 0; m < 8; ++m)
            #pragma unroll
            for (int n = m; n < 8; ++n) {
                int row = tb * 128 + m * 16 + rq;
                int col = tb * 128 + n * 16 + l15;
                #pragma unroll
                for (int j = 0; j < 4; ++j)
                    atomicAdd(&gout[(size_t)(row + j) * C_CH + col], acc[36 + TRI(m, n)][j]);
            }
    }
}

__global__ void norm_kernel(const float* __restrict__ gram, float* __restrict__ invn) {
    const int g = blockIdx.x, c = threadIdx.x;
    float v = gram[(size_t)g * CC + (size_t)c * C_CH + c];
    invn[g * C_CH + c] = 1.0f / sqrtf(v);
}

__global__ __launch_bounds__(256) void loss_kernel(const float* __restrict__ gram,
                                                   const float* __restrict__ invn,
                                                   float* __restrict__ partials) {
    const int tid = threadIdx.x;
    float s = 0.f;
    for (int idx = blockIdx.x * 256 + tid; idx < NB * CC; idx += LOSS_BLOCKS * 256) {
        int b = idx >> 18;
        int c = (idx >> 9) & 511;
        int d = idx & 511;
        int cc = c, dd = d;
        if (dd < cc) { int tmp = cc; cc = dd; dd = tmp; }   // upper triangle stored
        float gd = gram[(size_t)b * CC + (size_t)cc * C_CH + dd];
        float gs = gram[(size_t)(8 + b) * CC + (size_t)cc * C_CH + dd];
        float sd = gd * invn[b * C_CH + c] * invn[b * C_CH + d];
        float ss = gs * invn[(8 + b) * C_CH + c] * invn[(8 + b) * C_CH + d];
        float diff = sd - ss;
        s += diff * diff;
    }
    #pragma unroll
    for (int off = 32; off > 0; off >>= 1) s += __shfl_down(s, off, 64);
    __shared__ float red[4];
    if ((tid & 63) == 0) red[tid >> 6] = s;
    __syncthreads();
    if (tid == 0) partials[blockIdx.x] = red[0] + red[1] + red[2] + red[3];
}

__global__ void final_kernel(const float* __restrict__ partials, float* __restrict__ out) {
    const int tid = threadIdx.x;  // 256
    float s = 0.f;
    for (int i = tid; i < LOSS_BLOCKS; i += 256) s += partials[i];
    #pragma unroll
    for (int off = 32; off > 0; off >>= 1) s += __shfl_down(s, off, 64);
    __shared__ float red[4];
    if ((tid & 63) == 0) red[tid >> 6] = s;
    __syncthreads();
    if (tid == 0) out[0] = (red[0] + red[1] + red[2] + red[3]) * (1.0f / (float)(NB * (size_t)CC));
}

extern "C" void kernel_launch(void* const* d_in, const int* in_sizes, int n_in,
                              void* d_out, int out_size, void* d_ws, size_t ws_size,
                              hipStream_t stream) {
    const float* det = (const float*)d_in[0];
    const float* sr  = (const float*)d_in[1];
    float* gram     = (float*)d_ws;                       // 16 * 512 * 512 f32 = 16.78 MB
    float* invn     = gram + (size_t)NGRAM * CC;
    float* partials = invn + NGRAM * C_CH;
    float* out      = (float*)d_out;

    hipMemsetAsync(gram, 0, (size_t)NGRAM * CC * sizeof(float), stream);
    gram_kernel<<<NGRAM * KSPLIT, 512, 0, stream>>>(det, sr, gram);
    norm_kernel<<<NGRAM, C_CH, 0, stream>>>(gram, invn);
    loss_kernel<<<LOSS_BLOCKS, 256, 0, stream>>>(gram, invn, partials);
    final_kernel<<<1, 256, 0, stream>>>(partials, out);
}

// Round 10
// 433.724 us; speedup vs baseline: 1.5878x; 1.5878x over previous
//
#include <hip/hip_runtime.h>
#include <hip/hip_bf16.h>

#define C_CH 512
#define HW 16384
#define NB 8
#define TILE 256
#define BK 32                    // f32 k-elements per K-step (= MFMA K in bf16)
#define NTILES 3                 // (0,0),(0,1),(1,1) at 256 granularity
#define KSPLIT 16
#define KCHUNK (HW / KSPLIT)     // 1024
#define KSTEPS (KCHUNK / BK)     // 32
#define NGRAM 16
#define CC (C_CH * C_CH)
#define LOSS_BLOCKS 1024
#define GRID (NGRAM * NTILES * KSPLIT)   // 768 = 8 XCDs * 96
#define PANEL_V8 (TILE * BK / 8)         // 1024 bf16x8 slots = 16 KiB per panel

typedef float f32x4 __attribute__((ext_vector_type(4)));
typedef float f32x8 __attribute__((ext_vector_type(8)));
typedef __bf16 bf16x8 __attribute__((ext_vector_type(8)));

// raw barrier: LDS-drain only (loads issued for the next tile are already
// consumed by WRITE before we get here; avoids the syncthreads vmcnt(0) habit)
#define BAR()                                                       \
    do {                                                            \
        asm volatile("s_waitcnt lgkmcnt(0)" ::: "memory");          \
        __builtin_amdgcn_s_barrier();                               \
    } while (0)

// LDS slot for (row R, k-chunk c in 0..3): measured-zero-conflict pattern
// (R4/R5/R7). Row-pairs share a 128B line; XOR spreads quarter-wave reads.
__device__ __forceinline__ int slot_of(int R, int c) {
    return (R >> 1) * 8 + ((((R & 1) << 2) + c) ^ ((R >> 1) & 7));
}

// Gram SYRK: 256x256 triangular tiles (2x issue amplification vs 4x at 128^2 —
// the reg-staging issue path is the measured ~16 B/cyc/CU wall), 8 waves (2x4),
// bf16 LDS double-buffer with slot_of swizzle, depth-1 reg pipeline.
__global__ __launch_bounds__(512) void gram_kernel(const float* __restrict__ det,
                                                   const float* __restrict__ sr,
                                                   float* __restrict__ gram) {
    // XCD clustering: xcd X serves grams 2X, 2X+1; within an XCD the 3 tiles
    // of each (g,ks) are adjacent -> shared panels L2-resident
    const int bid = (int)blockIdx.x;
    const int idx = bid >> 3;            // 0..95 within XCD
    const int g = (bid & 7) * 2 + idx / 48;
    const int rem = idx % 48;
    const int ks = rem / 3;
    const int t = rem % 3;
    const int tensor = g >> 3, b = g & 7;
    const int ti = (t == 2) ? 1 : 0;
    const int tj = (t == 0) ? 0 : 1;
    const bool diag = (t != 1);

    const float* F = (tensor ? sr : det) + (size_t)b * C_CH * HW;
    const float* Abase = F + (size_t)(ti * TILE) * HW + ks * KCHUNK;
    const float* Bbase = F + (size_t)(tj * TILE) * HW + ks * KCHUNK;

    __shared__ bf16x8 lds[4 * PANEL_V8];   // [buf0 A|B][buf1 A|B] = 64 KiB

    const int tid = threadIdx.x;
    const int lane = tid & 63;
    const int wid = tid >> 6;
    const int wr = wid >> 2, wc = wid & 3;   // 2x4 waves -> per-wave 128x64

    // staging: panel = 256 rows x 4 chunks(8 f32) = 1024 chunks / 512 thr = 2 each
    int goff[2], lslot[2];
    #pragma unroll
    for (int q = 0; q < 2; ++q) {
        int c = q * 512 + tid;
        int r = c >> 2, ch = c & 3;
        goff[q] = r * HW + ch * 8;
        lslot[q] = slot_of(r, ch);
    }

    f32x8 va[2], vb[2];
    auto LOAD = [&](int kt) {
        const int ko = kt * BK;
        #pragma unroll
        for (int q = 0; q < 2; ++q) va[q] = *(const f32x8*)(Abase + goff[q] + ko);
        if (!diag) {
            #pragma unroll
            for (int q = 0; q < 2; ++q) vb[q] = *(const f32x8*)(Bbase + goff[q] + ko);
        }
    };
    auto WRITE = [&](int buf) {
        bf16x8* As = lds + buf * 2 * PANEL_V8;
        #pragma unroll
        for (int q = 0; q < 2; ++q) {
            bf16x8 h;
            #pragma unroll
            for (int i = 0; i < 8; ++i) h[i] = (__bf16)va[q][i];
            As[lslot[q]] = h;
        }
        if (!diag) {
            bf16x8* Bs = As + PANEL_V8;
            #pragma unroll
            for (int q = 0; q < 2; ++q) {
                bf16x8 h;
                #pragma unroll
                for (int i = 0; i < 8; ++i) h[i] = (__bf16)vb[q][i];
                Bs[lslot[q]] = h;
            }
        }
    };

    f32x4 acc[8][4] = {};
    const int kg = lane >> 4;            // k-chunk of this lane's fragment
    const int l15 = lane & 15;
    auto COMPUTE = [&](const bf16x8* As) {
        const bf16x8* Bs = diag ? As : As + PANEL_V8;
        bf16x8 af[8], bfr[4];
        #pragma unroll
        for (int m = 0; m < 8; ++m) {
            int R = wr * 128 + m * 16 + l15;
            af[m] = As[slot_of(R, kg)];
        }
        #pragma unroll
        for (int n = 0; n < 4; ++n) {
            int R = wc * 64 + n * 16 + l15;
            bfr[n] = Bs[slot_of(R, kg)];
        }
        __builtin_amdgcn_s_setprio(1);
        #pragma unroll
        for (int m = 0; m < 8; ++m)
            #pragma unroll
            for (int n = 0; n < 4; ++n)
                if (!diag || (wc * 64 + n * 16 + 16 > wr * 128 + m * 16))
                    acc[m][n] = __builtin_amdgcn_mfma_f32_16x16x32_bf16(af[m], bfr[n], acc[m][n], 0, 0, 0);
        __builtin_amdgcn_s_setprio(0);
    };

    // prologue
    LOAD(0);
    WRITE(0);
    BAR();
    int cur = 0;

    #pragma unroll 1
    for (int kt = 0; kt < KSTEPS; ++kt) {
        if (kt + 1 < KSTEPS) LOAD(kt + 1);     // issue early; COMPUTE covers latency
        COMPUTE(lds + cur * 2 * PANEL_V8);
        if (kt + 1 < KSTEPS) WRITE(cur ^ 1);   // compiler-counted vmcnt on own loads
        BAR();
        cur ^= 1;
    }

    // epilogue: C/D layout col=lane&15, row=(lane>>4)*4+j; skip below-diag frags
    float* gout = gram + (size_t)g * CC;
    const int rb = ti * TILE + wr * 128 + (kg << 2);
    const int cb = tj * TILE + wc * 64 + l15;
    #pragma unroll
    for (int m = 0; m < 8; ++m)
        #pragma unroll
        for (int n = 0; n < 4; ++n) {
            if (diag && (wc * 64 + n * 16 + 16 <= wr * 128 + m * 16)) continue;
            #pragma unroll
            for (int j = 0; j < 4; ++j)
                atomicAdd(&gout[(size_t)(rb + m * 16 + j) * C_CH + cb + n * 16], acc[m][n][j]);
        }
}

__global__ void norm_kernel(const float* __restrict__ gram, float* __restrict__ invn) {
    const int g = blockIdx.x, c = threadIdx.x;
    float v = gram[(size_t)g * CC + (size_t)c * C_CH + c];
    invn[g * C_CH + c] = 1.0f / sqrtf(v);
}

__global__ __launch_bounds__(256) void loss_kernel(const float* __restrict__ gram,
                                                   const float* __restrict__ invn,
                                                   float* __restrict__ partials) {
    const int tid = threadIdx.x;
    float s = 0.f;
    for (int idx = blockIdx.x * 256 + tid; idx < NB * CC; idx += LOSS_BLOCKS * 256) {
        int b = idx >> 18;
        int c = (idx >> 9) & 511;
        int d = idx & 511;
        int cc = c, dd = d;
        if (dd < cc) { int tmp = cc; cc = dd; dd = tmp; }   // upper triangle stored
        float gd = gram[(size_t)b * CC + (size_t)cc * C_CH + dd];
        float gs = gram[(size_t)(8 + b) * CC + (size_t)cc * C_CH + dd];
        float sd = gd * invn[b * C_CH + c] * invn[b * C_CH + d];
        float ss = gs * invn[(8 + b) * C_CH + c] * invn[(8 + b) * C_CH + d];
        float diff = sd - ss;
        s += diff * diff;
    }
    #pragma unroll
    for (int off = 32; off > 0; off >>= 1) s += __shfl_down(s, off, 64);
    __shared__ float red[4];
    if ((tid & 63) == 0) red[tid >> 6] = s;
    __syncthreads();
    if (tid == 0) partials[blockIdx.x] = red[0] + red[1] + red[2] + red[3];
}

__global__ void final_kernel(const float* __restrict__ partials, float* __restrict__ out) {
    const int tid = threadIdx.x;  // 256
    float s = 0.f;
    for (int i = tid; i < LOSS_BLOCKS; i += 256) s += partials[i];
    #pragma unroll
    for (int off = 32; off > 0; off >>= 1) s += __shfl_down(s, off, 64);
    __shared__ float red[4];
    if ((tid & 63) == 0) red[tid >> 6] = s;
    __syncthreads();
    if (tid == 0) out[0] = (red[0] + red[1] + red[2] + red[3]) * (1.0f / (float)(NB * (size_t)CC));
}

extern "C" void kernel_launch(void* const* d_in, const int* in_sizes, int n_in,
                              void* d_out, int out_size, void* d_ws, size_t ws_size,
                              hipStream_t stream) {
    const float* det = (const float*)d_in[0];
    const float* sr  = (const float*)d_in[1];
    float* gram     = (float*)d_ws;                       // 16 * 512 * 512 f32 = 16.78 MB
    float* invn     = gram + (size_t)NGRAM * CC;
    float* partials = invn + NGRAM * C_CH;
    float* out      = (float*)d_out;

    hipMemsetAsync(gram, 0, (size_t)NGRAM * CC * sizeof(float), stream);
    gram_kernel<<<GRID, 512, 0, stream>>>(det, sr, gram);
    norm_kernel<<<NGRAM, C_CH, 0, stream>>>(gram, invn);
    loss_kernel<<<LOSS_BLOCKS, 256, 0, stream>>>(gram, invn, partials);
    final_kernel<<<1, 256, 0, stream>>>(partials, out);
}

// Round 11
// 270.178 us; speedup vs baseline: 2.5489x; 1.6053x over previous
//
#include <hip/hip_runtime.h>
#include <hip/hip_bf16.h>

#define C_CH 512
#define HW 16384
#define NB 8
#define TILE 128
#define BK 32                    // f32 k-elements per K-step (= MFMA K in bf16)
#define NTB 4                    // C_CH / TILE
#define NTILES 10                // upper-triangular 128^2 tiles
#define KSPLIT 8
#define KCHUNK (HW / KSPLIT)     // 2048
#define KSTEPS (KCHUNK / BK)     // 64
#define NGRAM 16
#define CC (C_CH * C_CH)
#define LOSS_BLOCKS 1024
#define GRID (NGRAM * KSPLIT * NTILES)   // 1280 = 8 XCDs * 160
#define PANEL_SLOTS (TILE * 8)           // 1024 f32x4 = 16 KiB per panel

typedef float f32x4 __attribute__((ext_vector_type(4)));
typedef __bf16 bf16x8 __attribute__((ext_vector_type(8)));

#define GLOAD_LDS16(gsrc, ldst)                                                 \
    __builtin_amdgcn_global_load_lds(                                           \
        (const __attribute__((address_space(1))) void*)(gsrc),                  \
        (__attribute__((address_space(3))) void*)(ldst), 16, 0, 0)

// Gram SYRK: 128x128 triangular tiles, 4 waves (2x2), f32 LDS double-buffer
// staged by global_load_lds (no reg round-trip: the reg-staged issue path
// measured ~12-16 B/cyc/CU across R1/R4/R7; gload_lds sustains ~44 in m97).
// T3/T4 2-phase: counted vmcnt keeps next tile's DMA in flight across both
// barriers; bf16 conversion happens at fragment read.
__global__ __launch_bounds__(256, 2) void gram_kernel(const float* __restrict__ det,
                                                      const float* __restrict__ sr,
                                                      float* __restrict__ gram) {
    // grouped chunked XCD swizzle: all tiles/ksplits of one g on one XCD
    const int bid = (int)blockIdx.x;
    const int lbid = (bid & 7) * (GRID / 8) + (bid >> 3);
    const int t = lbid % NTILES;
    const int gk = lbid / NTILES;        // = g*KSPLIT + ks
    const int ks = gk & (KSPLIT - 1);
    const int g = gk >> 3;
    const int tensor = g >> 3, b = g & 7;

    int ti = 0, tt = t;
    while (tt >= NTB - ti) { tt -= NTB - ti; ++ti; }
    const int tj = ti + tt;
    const bool diag = (ti == tj);

    const float* F = (tensor ? sr : det) + (size_t)b * C_CH * HW;
    const float* Abase = F + (size_t)(ti * TILE) * HW + ks * KCHUNK;
    const float* Bbase = F + (size_t)(tj * TILE) * HW + ks * KCHUNK;

    __shared__ f32x4 lds[2][2][PANEL_SLOTS];   // [buf][A,B] f32 = 64 KiB

    const int tid = threadIdx.x;
    const int lane = tid & 63;
    const int wid = tid >> 6;
    const int wr = wid >> 1, wc = wid & 1;   // 2x2 waves -> per-wave 64x64
    const int kg = lane >> 4;                // k-chunk pair selector (2kg, 2kg+1)
    const int l15 = lane & 15;

    // STAGE: LDS dest LINEAR in f (wave-uniform base + lane*16 -- HW rule);
    // logical (row R=f>>3, slot s=f&7) holds global chunk c = s ^ (R&7)
    // (involution; fragment read applies the same XOR). 4 instrs/thread/panel.
    auto STAGE = [&](int buf, int kt) {
        const float* sA = Abase + kt * BK;
        #pragma unroll
        for (int q = 0; q < 4; ++q) {
            int f = q * 256 + tid;
            int R = f >> 3, s = f & 7;
            int c = s ^ (R & 7);
            GLOAD_LDS16(sA + (size_t)R * HW + c * 4, &lds[buf][0][f]);
        }
        if (!diag) {
            const float* sB = Bbase + kt * BK;
            #pragma unroll
            for (int q = 0; q < 4; ++q) {
                int f = q * 256 + tid;
                int R = f >> 3, s = f & 7;
                int c = s ^ (R & 7);
                GLOAD_LDS16(sB + (size_t)R * HW + c * 4, &lds[buf][1][f]);
            }
        }
    };

    // fragment read: 8 f32 of k-range kg*8..kg*8+7 from chunks 2kg,2kg+1
    // (XOR-inverted), convert to bf16x8
    auto rdfrag = [&](const f32x4* P, int R) {
        f32x4 lo = P[R * 8 + ((2 * kg) ^ (R & 7))];
        f32x4 hi = P[R * 8 + ((2 * kg + 1) ^ (R & 7))];
        bf16x8 h;
        #pragma unroll
        for (int i = 0; i < 4; ++i) { h[i] = (__bf16)lo[i]; h[4 + i] = (__bf16)hi[i]; }
        return h;
    };

    f32x4 acc[4][4] = {};
    auto COMPUTE = [&](int buf) {
        const f32x4* As = &lds[buf][0][0];
        const f32x4* Bs = diag ? As : &lds[buf][1][0];
        bf16x8 af[4], bfr[4];
        #pragma unroll
        for (int m = 0; m < 4; ++m) af[m] = rdfrag(As, wr * 64 + m * 16 + l15);
        #pragma unroll
        for (int n = 0; n < 4; ++n) bfr[n] = rdfrag(Bs, wc * 64 + n * 16 + l15);
        #pragma unroll
        for (int m = 0; m < 4; ++m)
            #pragma unroll
            for (int n = 0; n < 4; ++n)
                if (!diag || (wc * 64 + n * 16 + 16 > wr * 64 + m * 16))
                    acc[m][n] = __builtin_amdgcn_mfma_f32_16x16x32_bf16(af[m], bfr[n], acc[m][n], 0, 0, 0);
    };

    // 2-phase pipeline: stage(t) -> buf[t&1]; while computing buf[t&1],
    // stage(t+1)'s DMA stays in flight (counted vmcnt, never 0 mid-loop).
    STAGE(0, 0);
    #pragma unroll 1
    for (int kt = 0; kt < KSTEPS; ++kt) {
        if (kt + 1 < KSTEPS) {
            STAGE((kt + 1) & 1, kt + 1);
            // wait for stage(kt) only: stage(kt+1)'s loads (8 / 4) remain outstanding
            if (diag) asm volatile("s_waitcnt vmcnt(4)" ::: "memory");
            else      asm volatile("s_waitcnt vmcnt(8)" ::: "memory");
        } else {
            asm volatile("s_waitcnt vmcnt(0)" ::: "memory");
        }
        __builtin_amdgcn_s_barrier();
        asm volatile("" ::: "memory");
        COMPUTE(kt & 1);
        asm volatile("s_waitcnt lgkmcnt(0)" ::: "memory");   // reads done before next overwrite
        __builtin_amdgcn_s_barrier();
        asm volatile("" ::: "memory");
    }

    // epilogue: C/D layout col=lane&15, row=(lane>>4)*4+j; skip below-diag frags
    float* gout = gram + (size_t)g * CC;
    const int rb = ti * TILE + wr * 64 + (kg << 2);
    const int cb = tj * TILE + wc * 64 + l15;
    #pragma unroll
    for (int m = 0; m < 4; ++m)
        #pragma unroll
        for (int n = 0; n < 4; ++n) {
            if (diag && (wc * 64 + n * 16 + 16 <= wr * 64 + m * 16)) continue;
            #pragma unroll
            for (int j = 0; j < 4; ++j)
                atomicAdd(&gout[(size_t)(rb + m * 16 + j) * C_CH + cb + n * 16], acc[m][n][j]);
        }
}

__global__ void norm_kernel(const float* __restrict__ gram, float* __restrict__ invn) {
    const int g = blockIdx.x, c = threadIdx.x;
    float v = gram[(size_t)g * CC + (size_t)c * C_CH + c];
    invn[g * C_CH + c] = 1.0f / sqrtf(v);
}

__global__ __launch_bounds__(256) void loss_kernel(const float* __restrict__ gram,
                                                   const float* __restrict__ invn,
                                                   float* __restrict__ partials) {
    const int tid = threadIdx.x;
    float s = 0.f;
    for (int idx = blockIdx.x * 256 + tid; idx < NB * CC; idx += LOSS_BLOCKS * 256) {
        int b = idx >> 18;
        int c = (idx >> 9) & 511;
        int d = idx & 511;
        int cc = c, dd = d;
        if (dd < cc) { int tmp = cc; cc = dd; dd = tmp; }   // upper triangle stored
        float gd = gram[(size_t)b * CC + (size_t)cc * C_CH + dd];
        float gs = gram[(size_t)(8 + b) * CC + (size_t)cc * C_CH + dd];
        float sd = gd * invn[b * C_CH + c] * invn[b * C_CH + d];
        float ss = gs * invn[(8 + b) * C_CH + c] * invn[(8 + b) * C_CH + d];
        float diff = sd - ss;
        s += diff * diff;
    }
    #pragma unroll
    for (int off = 32; off > 0; off >>= 1) s += __shfl_down(s, off, 64);
    __shared__ float red[4];
    if ((tid & 63) == 0) red[tid >> 6] = s;
    __syncthreads();
    if (tid == 0) partials[blockIdx.x] = red[0] + red[1] + red[2] + red[3];
}

__global__ void final_kernel(const float* __restrict__ partials, float* __restrict__ out) {
    const int tid = threadIdx.x;  // 256
    float s = 0.f;
    for (int i = tid; i < LOSS_BLOCKS; i += 256) s += partials[i];
    #pragma unroll
    for (int off = 32; off > 0; off >>= 1) s += __shfl_down(s, off, 64);
    __shared__ float red[4];
    if ((tid & 63) == 0) red[tid >> 6] = s;
    __syncthreads();
    if (tid == 0) out[0] = (red[0] + red[1] + red[2] + red[3]) * (1.0f / (float)(NB * (size_t)CC));
}

extern "C" void kernel_launch(void* const* d_in, const int* in_sizes, int n_in,
                              void* d_out, int out_size, void* d_ws, size_t ws_size,
                              hipStream_t stream) {
    const float* det = (const float*)d_in[0];
    const float* sr  = (const float*)d_in[1];
    float* gram     = (float*)d_ws;                       // 16 * 512 * 512 f32 = 16.78 MB
    float* invn     = gram + (size_t)NGRAM * CC;
    float* partials = invn + NGRAM * C_CH;
    float* out      = (float*)d_out;

    hipMemsetAsync(gram, 0, (size_t)NGRAM * CC * sizeof(float), stream);
    gram_kernel<<<GRID, 256, 0, stream>>>(det, sr, gram);
    norm_kernel<<<NGRAM, C_CH, 0, stream>>>(gram, invn);
    loss_kernel<<<LOSS_BLOCKS, 256, 0, stream>>>(gram, invn, partials);
    final_kernel<<<1, 256, 0, stream>>>(partials, out);
}